// Round 1
// baseline (107.315 us; speedup 1.0000x reference)
//
#include <hip/hip_runtime.h>

#define NTOK 1048576
#define HID 64
#define TPB 256
#define TPB_TOK 2048
#define RPT (TPB_TOK / TPB)          // 8 tokens per thread in phase A
#define NBLK (NTOK / TPB_TOK)        // 512 blocks
#define MAXSLOT (TPB_TOK + 64)       // binned slots incl. 16-pad per expert
#define MAXTILE (TPB_TOK / 16 + 4)

typedef _Float16 half8 __attribute__((ext_vector_type(8)));
typedef float f32x4 __attribute__((ext_vector_type(4)));

// Convert w2 (E,HID,HID) fp32 -> f16 MFMA A-operand fragments for the
// transposed GEMM h2^T = w2^T @ h1^T.
// A[m=hid_out][k=hid_in]; frag elem (e, mt, ks, lane, j):
//   m = mt*16 + (lane&15), k = ks*32 + (lane>>4)*8 + j  -> w2[e][k][m]
__global__ void prep_w2_frag(const float* __restrict__ w2, _Float16* __restrict__ wsf) {
    int idx  = blockIdx.x * 256 + threadIdx.x;   // 0..16383
    int j    = idx & 7;
    int lane = (idx >> 3) & 63;
    int ks   = (idx >> 9) & 1;
    int mt   = (idx >> 10) & 3;
    int e    = idx >> 12;
    int kin  = ks * 32 + (lane >> 4) * 8 + j;
    int m    = mt * 16 + (lane & 15);
    wsf[idx] = (_Float16)w2[(e * HID + kin) * HID + m];
}

__global__ __launch_bounds__(TPB, 2) void moe_kernel(
    const float* __restrict__ x, const float* __restrict__ rW, const float* __restrict__ rb,
    const float* __restrict__ w1, const float* __restrict__ b1,
    const float* __restrict__ b2,
    const float* __restrict__ w3, const float* __restrict__ b3,
    const _Float16* __restrict__ wsf, float* __restrict__ out)
{
    __shared__ float2 xs[MAXSLOT];
    __shared__ int ids[MAXSLOT];
    __shared__ int wcnt[4][4];                  // [wave][expert]
    __shared__ int seg_start[4], cnt_sh[4], cumt[5];
    __shared__ unsigned tmap[MAXTILE];

    const int t = threadIdx.x, w = t >> 6, lane = t & 63;
    const int base = blockIdx.x * TPB_TOK;
    const unsigned long long lt = (1ull << lane) - 1ull;

    // ---------------- Phase A: router + binning ----------------
    const float r00 = rW[0], r01 = rW[1], r02 = rW[2], r03 = rW[3];
    const float r10 = rW[4], r11 = rW[5], r12 = rW[6], r13 = rW[7];
    const float rb0 = rb[0], rb1 = rb[1], rb2 = rb[2], rb3 = rb[3];

    int c0 = 0, c1 = 0, c2 = 0, c3 = 0;
    int slotl[RPT]; int bestl[RPT]; float2 xv_[RPT];
    float* logits_out = out + 2 * NTOK;
    #pragma unroll
    for (int i = 0; i < RPT; i++) {
        int tok = base + i * TPB + t;
        float2 xv = ((const float2*)x)[tok];
        float l0 = xv.x * r00 + xv.y * r10 + rb0;
        float l1 = xv.x * r01 + xv.y * r11 + rb1;
        float l2 = xv.x * r02 + xv.y * r12 + rb2;
        float l3 = xv.x * r03 + xv.y * r13 + rb3;
        ((float4*)logits_out)[tok] = make_float4(l0, l1, l2, l3);
        int b = 0; float bv = l0;
        if (l1 > bv) { bv = l1; b = 1; }
        if (l2 > bv) { bv = l2; b = 2; }
        if (l3 > bv) { bv = l3; b = 3; }
        unsigned long long m0 = __ballot(b == 0), m1 = __ballot(b == 1),
                           m2 = __ballot(b == 2), m3 = __ballot(b == 3);
        unsigned long long mym = (b == 0) ? m0 : (b == 1) ? m1 : (b == 2) ? m2 : m3;
        int cb = (b == 0) ? c0 : (b == 1) ? c1 : (b == 2) ? c2 : c3;
        slotl[i] = cb + __popcll(mym & lt);
        bestl[i] = b; xv_[i] = xv;
        c0 += __popcll(m0); c1 += __popcll(m1); c2 += __popcll(m2); c3 += __popcll(m3);
    }
    if (lane < 4) wcnt[w][lane] = (lane == 0) ? c0 : (lane == 1) ? c1 : (lane == 2) ? c2 : c3;
    __syncthreads();
    if (t == 0) {
        int run = 0, ct = 0; cumt[0] = 0;
        for (int e = 0; e < 4; e++) {
            int c = wcnt[0][e] + wcnt[1][e] + wcnt[2][e] + wcnt[3][e];
            cnt_sh[e] = c; seg_start[e] = run;
            run += (c + 15) & ~15; ct += (c + 15) >> 4; cumt[e + 1] = ct;
        }
    }
    __syncthreads();
    int wo0 = 0, wo1 = 0, wo2 = 0, wo3 = 0;
    for (int ww = 0; ww < w; ww++) {
        wo0 += wcnt[ww][0]; wo1 += wcnt[ww][1]; wo2 += wcnt[ww][2]; wo3 += wcnt[ww][3];
    }
    #pragma unroll
    for (int i = 0; i < RPT; i++) {
        int b = bestl[i];
        int wo = (b == 0) ? wo0 : (b == 1) ? wo1 : (b == 2) ? wo2 : wo3;
        int slot = seg_start[b] + wo + slotl[i];
        xs[slot] = xv_[i];
        ids[slot] = base + i * TPB + t;
    }
    int T = cumt[4];
    for (int g = t; g < T; g += TPB) {
        int e = (g >= cumt[1]) + (g >= cumt[2]) + (g >= cumt[3]);
        int i = g - cumt[e];
        int row = seg_start[e] + 16 * i;
        int cn = cnt_sh[e] - 16 * i; if (cn > 16) cn = 16;
        tmap[g] = (unsigned)e | ((unsigned)row << 2) | ((unsigned)cn << 18);
    }
    __syncthreads();

    // ---------------- Phase B: per-tile MFMA ----------------
    const int q = lane >> 4, n16 = lane & 15;
    int chunk = (T + 3) >> 2;
    int g0 = w * chunk, g1 = g0 + chunk; if (g1 > T) g1 = T;

    float w1r0[16], w1r1[16], b1r[16];
    half8 w2A[4][2];
    float4 b2r[4], w3a[4], w3b[4];
    float2 b3r = make_float2(0.f, 0.f);
    int cur_e = -1;

    for (int g = g0; g < g1; g++) {
        unsigned tm = tmap[g];
        int e   = tm & 3;
        int row = (tm >> 2) & 0xFFF;
        int cn  = tm >> 18;
        if (e != cur_e) {   // wave-uniform branch
            cur_e = e;
            const float* p0 = w1 + e * 128 + q * 8;          // w1[e][0][cols]
            const float* p1 = w1 + e * 128 + 64 + q * 8;     // w1[e][1][cols]
            const float* pb = b1 + e * 64 + q * 8;
            #pragma unroll
            for (int j = 0; j < 8; j++) {
                w1r0[j] = p0[j];  w1r0[8 + j] = p0[32 + j];
                w1r1[j] = p1[j];  w1r1[8 + j] = p1[32 + j];
                b1r[j]  = pb[j];  b1r[8 + j]  = pb[32 + j];
            }
            #pragma unroll
            for (int mt = 0; mt < 4; mt++) {
                w2A[mt][0] = ((const half8*)wsf)[((e * 4 + mt) * 2 + 0) * 64 + lane];
                w2A[mt][1] = ((const half8*)wsf)[((e * 4 + mt) * 2 + 1) * 64 + lane];
                b2r[mt] = ((const float4*)(b2 + e * 64))[mt * 4 + q];
                w3a[mt] = ((const float4*)(w3 + e * 128))[mt * 8 + q * 2];       // rows h0,h1
                w3b[mt] = ((const float4*)(w3 + e * 128))[mt * 8 + q * 2 + 1];   // rows h2,h3
            }
            b3r = ((const float2*)b3)[e];
        }
        // h1 computed in fp32 directly into B-fragment registers:
        // B[k = ks*32 + q*8 + j][n = token n16]
        float2 xv = xs[row + n16];
        half8 bf0, bf1;
        #pragma unroll
        for (int j = 0; j < 8; j++) {
            float ha = fmaf(xv.y, w1r1[j],     fmaf(xv.x, w1r0[j],     b1r[j]));
            float hb = fmaf(xv.y, w1r1[8 + j], fmaf(xv.x, w1r0[8 + j], b1r[8 + j]));
            bf0[j] = (_Float16)fmaxf(ha, 0.f);
            bf1[j] = (_Float16)fmaxf(hb, 0.f);
        }
        float y0 = 0.f, y1 = 0.f;
        #pragma unroll
        for (int mt = 0; mt < 4; mt++) {
            f32x4 acc = {0.f, 0.f, 0.f, 0.f};
            acc = __builtin_amdgcn_mfma_f32_16x16x32_f16(w2A[mt][0], bf0, acc, 0, 0, 0);
            acc = __builtin_amdgcn_mfma_f32_16x16x32_f16(w2A[mt][1], bf1, acc, 0, 0, 0);
            // C-frag: col(token)=n16, row(hid_out)=mt*16+q*4+r  -> layer 3 in fp32
            float4 bb = b2r[mt], wa = w3a[mt], wb = w3b[mt];
            float h;
            h = fmaxf(acc[0] + bb.x, 0.f); y0 = fmaf(h, wa.x, y0); y1 = fmaf(h, wa.y, y1);
            h = fmaxf(acc[1] + bb.y, 0.f); y0 = fmaf(h, wa.z, y0); y1 = fmaf(h, wa.w, y1);
            h = fmaxf(acc[2] + bb.z, 0.f); y0 = fmaf(h, wb.x, y0); y1 = fmaf(h, wb.y, y1);
            h = fmaxf(acc[3] + bb.w, 0.f); y0 = fmaf(h, wb.z, y0); y1 = fmaf(h, wb.w, y1);
        }
        // reduce partial sums over the 4 lane-quads (hid_out split)
        y0 += __shfl_xor(y0, 16); y0 += __shfl_xor(y0, 32);
        y1 += __shfl_xor(y1, 16); y1 += __shfl_xor(y1, 32);
        if (q == 0 && n16 < cn) {
            int tok = ids[row + n16];
            ((float2*)out)[tok] = make_float2(y0 + b3r.x, y1 + b3r.y);
        }
    }
}

extern "C" void kernel_launch(void* const* d_in, const int* in_sizes, int n_in,
                              void* d_out, int out_size, void* d_ws, size_t ws_size,
                              hipStream_t stream) {
    const float* x  = (const float*)d_in[0];
    const float* rW = (const float*)d_in[1];
    const float* rb = (const float*)d_in[2];
    const float* w1 = (const float*)d_in[3];
    const float* b1 = (const float*)d_in[4];
    const float* w2 = (const float*)d_in[5];
    const float* b2 = (const float*)d_in[6];
    const float* w3 = (const float*)d_in[7];
    const float* b3 = (const float*)d_in[8];
    float* out = (float*)d_out;
    _Float16* wsf = (_Float16*)d_ws;

    hipLaunchKernelGGL(prep_w2_frag, dim3(64), dim3(256), 0, stream, w2, wsf);
    hipLaunchKernelGGL(moe_kernel, dim3(NBLK), dim3(TPB), 0, stream,
                       x, rW, rb, w1, b1, b2, w3, b3, (const _Float16*)wsf, out);
}

// Round 3
// 105.962 us; speedup vs baseline: 1.0128x; 1.0128x over previous
//
#include <hip/hip_runtime.h>

#define NTOK 1048576
#define HID 64
#define TPB 256
#define TPB_TOK 2048
#define RPT (TPB_TOK / TPB)          // 8 tokens per thread in phase A
#define NBLK (NTOK / TPB_TOK)        // 512 blocks = 2 blocks/CU, all resident
#define MAXSLOT (TPB_TOK + 64)       // binned slots incl. 16-pad per expert
#define MAXTILE (TPB_TOK / 16 + 4)

typedef _Float16 half8 __attribute__((ext_vector_type(8)));
typedef _Float16 half2v __attribute__((ext_vector_type(2)));
typedef float f32x4 __attribute__((ext_vector_type(4)));

static __device__ __forceinline__ half2v pkh(float a, float b) {
    return __builtin_bit_cast(half2v, __builtin_amdgcn_cvt_pkrtz(a, b));
}

// Convert w2 (E,HID,HID) fp32 -> f16 MFMA A-operand fragments for the
// transposed GEMM h2^T = w2^T @ h1^T.
// A[m=hid_out][k=hid_in]; frag elem (e, mt, ks, lane, j):
//   m = mt*16 + (lane&15), k = ks*32 + (lane>>4)*8 + j  -> w2[e][k][m]
__global__ void prep_w2_frag(const float* __restrict__ w2, _Float16* __restrict__ wsf) {
    int idx  = blockIdx.x * 256 + threadIdx.x;   // 0..16383
    int j    = idx & 7;
    int lane = (idx >> 3) & 63;
    int ks   = (idx >> 9) & 1;
    int mt   = (idx >> 10) & 3;
    int e    = idx >> 12;
    int kin  = ks * 32 + (lane >> 4) * 8 + j;
    int m    = mt * 16 + (lane & 15);
    wsf[idx] = (_Float16)w2[(e * HID + kin) * HID + m];
}

__global__ __launch_bounds__(TPB, 2) void moe_kernel(
    const float* __restrict__ x, const float* __restrict__ rW, const float* __restrict__ rb,
    const float* __restrict__ w1, const float* __restrict__ b1,
    const float* __restrict__ b2,
    const float* __restrict__ w3, const float* __restrict__ b3,
    const _Float16* __restrict__ wsf, float* __restrict__ out)
{
    __shared__ float2 xs[MAXSLOT];
    __shared__ int ids[MAXSLOT];
    __shared__ int wcnt[4][4];                  // [wave][expert]
    __shared__ int seg_start[4], cnt_sh[4], cumt[5];
    __shared__ unsigned tmap[MAXTILE];

    const int t = threadIdx.x, w = t >> 6, lane = t & 63;
    const int base = blockIdx.x * TPB_TOK;
    const unsigned long long lt = (1ull << lane) - 1ull;

    // ---------------- Phase A: router + binning (kept bit-identical) ----------------
    const float r00 = rW[0], r01 = rW[1], r02 = rW[2], r03 = rW[3];
    const float r10 = rW[4], r11 = rW[5], r12 = rW[6], r13 = rW[7];
    const float rb0 = rb[0], rb1 = rb[1], rb2 = rb[2], rb3 = rb[3];

    int c0 = 0, c1 = 0, c2 = 0, c3 = 0;
    int slotl[RPT]; int bestl[RPT]; float2 xv_[RPT];
    float* logits_out = out + 2 * NTOK;
    #pragma unroll
    for (int i = 0; i < RPT; i++) {
        int tok = base + i * TPB + t;
        float2 xv = ((const float2*)x)[tok];
        float l0 = xv.x * r00 + xv.y * r10 + rb0;
        float l1 = xv.x * r01 + xv.y * r11 + rb1;
        float l2 = xv.x * r02 + xv.y * r12 + rb2;
        float l3 = xv.x * r03 + xv.y * r13 + rb3;
        ((float4*)logits_out)[tok] = make_float4(l0, l1, l2, l3);
        int b = 0; float bv = l0;
        if (l1 > bv) { bv = l1; b = 1; }
        if (l2 > bv) { bv = l2; b = 2; }
        if (l3 > bv) { bv = l3; b = 3; }
        unsigned long long m0 = __ballot(b == 0), m1 = __ballot(b == 1),
                           m2 = __ballot(b == 2), m3 = __ballot(b == 3);
        unsigned long long mym = (b == 0) ? m0 : (b == 1) ? m1 : (b == 2) ? m2 : m3;
        int cb = (b == 0) ? c0 : (b == 1) ? c1 : (b == 2) ? c2 : c3;
        slotl[i] = cb + __popcll(mym & lt);
        bestl[i] = b; xv_[i] = xv;
        c0 += __popcll(m0); c1 += __popcll(m1); c2 += __popcll(m2); c3 += __popcll(m3);
    }
    if (lane < 4) wcnt[w][lane] = (lane == 0) ? c0 : (lane == 1) ? c1 : (lane == 2) ? c2 : c3;
    __syncthreads();
    if (t == 0) {
        int run = 0, ct = 0; cumt[0] = 0;
        for (int e = 0; e < 4; e++) {
            int c = wcnt[0][e] + wcnt[1][e] + wcnt[2][e] + wcnt[3][e];
            cnt_sh[e] = c; seg_start[e] = run;
            run += (c + 15) & ~15; ct += (c + 15) >> 4; cumt[e + 1] = ct;
        }
    }
    __syncthreads();
    int wo0 = 0, wo1 = 0, wo2 = 0, wo3 = 0;
    for (int ww = 0; ww < w; ww++) {
        wo0 += wcnt[ww][0]; wo1 += wcnt[ww][1]; wo2 += wcnt[ww][2]; wo3 += wcnt[ww][3];
    }
    #pragma unroll
    for (int i = 0; i < RPT; i++) {
        int b = bestl[i];
        int wo = (b == 0) ? wo0 : (b == 1) ? wo1 : (b == 2) ? wo2 : wo3;
        int slot = seg_start[b] + wo + slotl[i];
        xs[slot] = xv_[i];
        ids[slot] = base + i * TPB + t;
    }
    int T = cumt[4];
    for (int g = t; g < T; g += TPB) {
        int e = (g >= cumt[1]) + (g >= cumt[2]) + (g >= cumt[3]);
        int i = g - cumt[e];
        int row = seg_start[e] + 16 * i;
        int cn = cnt_sh[e] - 16 * i; if (cn > 16) cn = 16;
        tmap[g] = (unsigned)e | ((unsigned)row << 2) | ((unsigned)cn << 18);
    }
    __syncthreads();

    // ---------------- Phase B: per-tile MFMA ----------------
    const int q = lane >> 4, n16 = lane & 15;
    int chunk = (T + 3) >> 2;
    int g0 = w * chunk, g1 = g0 + chunk; if (g1 > T) g1 = T;

    // per-expert register state (f16-packed where possible)
    half2v w1h0[8], w1h1[8], b1h[8];     // lane's 16 hid slots as 8 half2 (ks0: p<4, ks1: p>=4)
    half8 w2A[4][2];
    float4 b2r[4], w3a[4], w3b[4];
    float2 b3r = make_float2(0.f, 0.f);
    int cur_e = -1;

    // prefetch pipeline
    unsigned tm_n = 0; float2 xv_n = make_float2(0.f, 0.f); int id_n = 0;
    if (g0 < g1) {
        tm_n = tmap[g0];
        int r_ = (tm_n >> 2) & 0xFFF;
        xv_n = xs[r_ + n16];
        id_n = ids[r_ + n16];
    }

    for (int g = g0; g < g1; g++) {
        unsigned tm = tm_n; float2 xv = xv_n; int idv = id_n;
        if (g + 1 < g1) {
            tm_n = tmap[g + 1];
            int r_ = (tm_n >> 2) & 0xFFF;
            xv_n = xs[r_ + n16];
            id_n = ids[r_ + n16];
        }
        int e  = tm & 3;
        int cn = tm >> 18;
        if (e != cur_e) {   // wave-uniform branch, ~4×/wave
            cur_e = e;
            const float* base0 = w1 + e * 128;        // w1[e][0][*]
            const float* base1 = w1 + e * 128 + 64;   // w1[e][1][*]
            const float* baseb = b1 + e * 64;
            #pragma unroll
            for (int p = 0; p < 4; p++) {
                float2 a0 = *(const float2*)(base0 + q * 8 + 2 * p);
                float2 a1 = *(const float2*)(base0 + 32 + q * 8 + 2 * p);
                w1h0[p]     = pkh(a0.x, a0.y);
                w1h0[4 + p] = pkh(a1.x, a1.y);
                float2 c0_ = *(const float2*)(base1 + q * 8 + 2 * p);
                float2 c1_ = *(const float2*)(base1 + 32 + q * 8 + 2 * p);
                w1h1[p]     = pkh(c0_.x, c0_.y);
                w1h1[4 + p] = pkh(c1_.x, c1_.y);
                float2 d0 = *(const float2*)(baseb + q * 8 + 2 * p);
                float2 d1 = *(const float2*)(baseb + 32 + q * 8 + 2 * p);
                b1h[p]     = pkh(d0.x, d0.y);
                b1h[4 + p] = pkh(d1.x, d1.y);
            }
            #pragma unroll
            for (int mt = 0; mt < 4; mt++) {
                w2A[mt][0] = ((const half8*)wsf)[((e * 4 + mt) * 2 + 0) * 64 + lane];
                w2A[mt][1] = ((const half8*)wsf)[((e * 4 + mt) * 2 + 1) * 64 + lane];
                b2r[mt] = ((const float4*)(b2 + e * 64))[mt * 4 + q];
                w3a[mt] = ((const float4*)(w3 + e * 128))[mt * 8 + q * 2];       // rows h0,h1
                w3b[mt] = ((const float4*)(w3 + e * 128))[mt * 8 + q * 2 + 1];   // rows h2,h3
            }
            b3r = ((const float2*)b3)[e];
        }
        // h1 in packed f16, directly into B-fragment layout:
        // B[k = ks*32 + q*8 + j][n = token n16]
        half2v xh0 = pkh(xv.x, xv.x);
        half2v xh1 = pkh(xv.y, xv.y);
        const half2v hz = { (_Float16)0, (_Float16)0 };
        half8 bf0, bf1;
        #pragma unroll
        for (int p = 0; p < 4; p++) {
            half2v ha = w1h0[p] * xh0 + w1h1[p] * xh1 + b1h[p];
            half2v hb = w1h0[4 + p] * xh0 + w1h1[4 + p] * xh1 + b1h[4 + p];
            ha = __builtin_elementwise_max(ha, hz);
            hb = __builtin_elementwise_max(hb, hz);
            bf0[2 * p] = ha.x; bf0[2 * p + 1] = ha.y;
            bf1[2 * p] = hb.x; bf1[2 * p + 1] = hb.y;
        }
        // layer 2 MFMA + layer 3 epilogue, 4 independent mt chains
        float y0m[4], y1m[4];
        #pragma unroll
        for (int mt = 0; mt < 4; mt++) {
            f32x4 acc = {0.f, 0.f, 0.f, 0.f};
            acc = __builtin_amdgcn_mfma_f32_16x16x32_f16(w2A[mt][0], bf0, acc, 0, 0, 0);
            acc = __builtin_amdgcn_mfma_f32_16x16x32_f16(w2A[mt][1], bf1, acc, 0, 0, 0);
            // C-frag: col(token)=n16, row(hid_out)=mt*16+q*4+r
            float4 bb = b2r[mt], wa = w3a[mt], wb = w3b[mt];
            float h, a0 = 0.f, a1 = 0.f;
            h = fmaxf(acc[0] + bb.x, 0.f); a0 = fmaf(h, wa.x, a0); a1 = fmaf(h, wa.y, a1);
            h = fmaxf(acc[1] + bb.y, 0.f); a0 = fmaf(h, wa.z, a0); a1 = fmaf(h, wa.w, a1);
            h = fmaxf(acc[2] + bb.z, 0.f); a0 = fmaf(h, wb.x, a0); a1 = fmaf(h, wb.y, a1);
            h = fmaxf(acc[3] + bb.w, 0.f); a0 = fmaf(h, wb.z, a0); a1 = fmaf(h, wb.w, a1);
            y0m[mt] = a0; y1m[mt] = a1;
        }
        float y0 = (y0m[0] + y0m[1]) + (y0m[2] + y0m[3]);
        float y1 = (y1m[0] + y1m[1]) + (y1m[2] + y1m[3]);
        // reduce partial sums over the 4 lane-quads (hid_out split)
        y0 += __shfl_xor(y0, 16); y0 += __shfl_xor(y0, 32);
        y1 += __shfl_xor(y1, 16); y1 += __shfl_xor(y1, 32);
        if (q == 0 && n16 < cn) {
            ((float2*)out)[idv] = make_float2(y0 + b3r.x, y1 + b3r.y);
        }
    }
}

extern "C" void kernel_launch(void* const* d_in, const int* in_sizes, int n_in,
                              void* d_out, int out_size, void* d_ws, size_t ws_size,
                              hipStream_t stream) {
    const float* x  = (const float*)d_in[0];
    const float* rW = (const float*)d_in[1];
    const float* rb = (const float*)d_in[2];
    const float* w1 = (const float*)d_in[3];
    const float* b1 = (const float*)d_in[4];
    const float* w2 = (const float*)d_in[5];
    const float* b2 = (const float*)d_in[6];
    const float* w3 = (const float*)d_in[7];
    const float* b3 = (const float*)d_in[8];
    float* out = (float*)d_out;
    _Float16* wsf = (_Float16*)d_ws;

    hipLaunchKernelGGL(prep_w2_frag, dim3(64), dim3(256), 0, stream, w2, wsf);
    hipLaunchKernelGGL(moe_kernel, dim3(NBLK), dim3(TPB), 0, stream,
                       x, rW, rb, w1, b1, b2, w3, b3, (const _Float16*)wsf, out);
}

// Round 4
// 102.394 us; speedup vs baseline: 1.0481x; 1.0348x over previous
//
#include <hip/hip_runtime.h>

#define NTOK 1048576
#define HID 64
#define TPB 256
#define TPB_TOK 1024
#define RPT (TPB_TOK / TPB)          // 4 tokens per thread in phase A/C
#define NBLK (NTOK / TPB_TOK)        // 1024 blocks = exactly 4 blocks/CU resident
#define MAXSLOT (TPB_TOK + 64)       // binned slots incl. 16-pad per expert
#define MAXTILE (TPB_TOK / 16 + 4)

typedef _Float16 half8 __attribute__((ext_vector_type(8)));
typedef _Float16 half2v __attribute__((ext_vector_type(2)));
typedef float f32x4 __attribute__((ext_vector_type(4)));

static __device__ __forceinline__ half2v pkh(float a, float b) {
    return __builtin_bit_cast(half2v, __builtin_amdgcn_cvt_pkrtz(a, b));
}

// Convert w2 (E,HID,HID) fp32 -> f16 MFMA A-operand fragments for the
// transposed GEMM h2^T = w2^T @ h1^T.
// A[m=hid_out][k=hid_in]; frag elem (e, mt, ks, lane, j):
//   m = mt*16 + (lane&15), k = ks*32 + (lane>>4)*8 + j  -> w2[e][k][m]
__global__ void prep_w2_frag(const float* __restrict__ w2, _Float16* __restrict__ wsf) {
    int idx  = blockIdx.x * 256 + threadIdx.x;   // 0..16383
    int j    = idx & 7;
    int lane = (idx >> 3) & 63;
    int ks   = (idx >> 9) & 1;
    int mt   = (idx >> 10) & 3;
    int e    = idx >> 12;
    int kin  = ks * 32 + (lane >> 4) * 8 + j;
    int m    = mt * 16 + (lane & 15);
    wsf[idx] = (_Float16)w2[(e * HID + kin) * HID + m];
}

__global__ __launch_bounds__(TPB, 4) void moe_kernel(
    const float* __restrict__ x, const float* __restrict__ rW, const float* __restrict__ rb,
    const float* __restrict__ w1, const float* __restrict__ b1,
    const float* __restrict__ b2,
    const float* __restrict__ w3, const float* __restrict__ b3,
    const _Float16* __restrict__ wsf, float* __restrict__ out)
{
    __shared__ float2 xs[MAXSLOT];
    __shared__ float2 ysh[MAXSLOT];
    __shared__ int wcnt[4][4];                  // [wave][expert]
    __shared__ int seg_start[4], cumt[5];
    __shared__ unsigned tmap[MAXTILE];

    const int t = threadIdx.x, w = t >> 6, lane = t & 63;
    const int base = blockIdx.x * TPB_TOK;
    const unsigned long long lt = (1ull << lane) - 1ull;

    // ---------------- Phase A: router + binning (argmax logic bit-identical) ----------------
    const float r00 = rW[0], r01 = rW[1], r02 = rW[2], r03 = rW[3];
    const float r10 = rW[4], r11 = rW[5], r12 = rW[6], r13 = rW[7];
    const float rb0 = rb[0], rb1 = rb[1], rb2 = rb[2], rb3 = rb[3];

    int c0 = 0, c1 = 0, c2 = 0, c3 = 0;
    int slotl[RPT]; int bestl[RPT]; float2 xv_[RPT]; int slotf[RPT];
    float* logits_out = out + 2 * NTOK;
    #pragma unroll
    for (int i = 0; i < RPT; i++) {
        int tok = base + i * TPB + t;
        float2 xv = ((const float2*)x)[tok];
        float l0 = xv.x * r00 + xv.y * r10 + rb0;
        float l1 = xv.x * r01 + xv.y * r11 + rb1;
        float l2 = xv.x * r02 + xv.y * r12 + rb2;
        float l3 = xv.x * r03 + xv.y * r13 + rb3;
        ((float4*)logits_out)[tok] = make_float4(l0, l1, l2, l3);
        int b = 0; float bv = l0;
        if (l1 > bv) { bv = l1; b = 1; }
        if (l2 > bv) { bv = l2; b = 2; }
        if (l3 > bv) { bv = l3; b = 3; }
        unsigned long long m0 = __ballot(b == 0), m1 = __ballot(b == 1),
                           m2 = __ballot(b == 2), m3 = __ballot(b == 3);
        unsigned long long mym = (b == 0) ? m0 : (b == 1) ? m1 : (b == 2) ? m2 : m3;
        int cb = (b == 0) ? c0 : (b == 1) ? c1 : (b == 2) ? c2 : c3;
        slotl[i] = cb + __popcll(mym & lt);
        bestl[i] = b; xv_[i] = xv;
        c0 += __popcll(m0); c1 += __popcll(m1); c2 += __popcll(m2); c3 += __popcll(m3);
    }
    if (lane < 4) wcnt[w][lane] = (lane == 0) ? c0 : (lane == 1) ? c1 : (lane == 2) ? c2 : c3;
    __syncthreads();
    if (t == 0) {
        int run = 0, ct = 0; cumt[0] = 0;
        for (int e = 0; e < 4; e++) {
            int c = wcnt[0][e] + wcnt[1][e] + wcnt[2][e] + wcnt[3][e];
            seg_start[e] = run;
            run += (c + 15) & ~15; ct += (c + 15) >> 4; cumt[e + 1] = ct;
        }
    }
    __syncthreads();
    int wo0 = 0, wo1 = 0, wo2 = 0, wo3 = 0;
    for (int ww = 0; ww < w; ww++) {
        wo0 += wcnt[ww][0]; wo1 += wcnt[ww][1]; wo2 += wcnt[ww][2]; wo3 += wcnt[ww][3];
    }
    #pragma unroll
    for (int i = 0; i < RPT; i++) {
        int b = bestl[i];
        int wo = (b == 0) ? wo0 : (b == 1) ? wo1 : (b == 2) ? wo2 : wo3;
        int slot = seg_start[b] + wo + slotl[i];
        xs[slot] = xv_[i];
        slotf[i] = slot;
    }
    int T = cumt[4];
    for (int g = t; g < T; g += TPB) {
        int e = (g >= cumt[1]) + (g >= cumt[2]) + (g >= cumt[3]);
        int i = g - cumt[e];
        int row = seg_start[e] + 16 * i;
        tmap[g] = (unsigned)e | ((unsigned)row << 2);
    }
    __syncthreads();

    // ---------------- Phase B: per-tile MFMA ----------------
    const int q = lane >> 4, n16 = lane & 15;
    int chunk = (T + 3) >> 2;
    int g0 = w * chunk, g1 = g0 + chunk; if (g1 > T) g1 = T;

    // per-expert register state (f16-packed)
    half2v w1h0[8], w1h1[8], b1h[8];   // lane's 16 hid slots as 8 half2 (ks0: p<4, ks1: p>=4)
    half8 w2A[4][2];                   // 32 VGPR
    half2v b2h[4][2];                  // 8
    half2v w3h[4][4];                  // 16: w3h[mt][i] = (w3[r][0], w3[r][1]), r=mt*16+q*4+i
    float2 b3r = make_float2(0.f, 0.f);
    int cur_e = -1;
    const half2v hz = { (_Float16)0, (_Float16)0 };

    // prefetch pipeline for tile metadata + x
    unsigned tm_n = 0; float2 xv_n = make_float2(0.f, 0.f);
    if (g0 < g1) {
        tm_n = tmap[g0];
        xv_n = xs[((tm_n >> 2) & 0xFFF) + n16];
    }

    for (int g = g0; g < g1; g++) {
        unsigned tm = tm_n; float2 xv = xv_n;
        if (g + 1 < g1) {
            tm_n = tmap[g + 1];
            xv_n = xs[((tm_n >> 2) & 0xFFF) + n16];
        }
        int e   = tm & 3;
        int row = (tm >> 2) & 0xFFF;
        if (e != cur_e) {   // wave-uniform, <=4x per wave (tiles expert-sorted)
            cur_e = e;
            const float* base0 = w1 + e * 128;        // w1[e][0][*]
            const float* base1 = w1 + e * 128 + 64;   // w1[e][1][*]
            const float* baseb = b1 + e * 64;
            #pragma unroll
            for (int p = 0; p < 4; p++) {
                float2 a0 = *(const float2*)(base0 + q * 8 + 2 * p);
                float2 a1 = *(const float2*)(base0 + 32 + q * 8 + 2 * p);
                w1h0[p]     = pkh(a0.x, a0.y);
                w1h0[4 + p] = pkh(a1.x, a1.y);
                float2 c0_ = *(const float2*)(base1 + q * 8 + 2 * p);
                float2 c1_ = *(const float2*)(base1 + 32 + q * 8 + 2 * p);
                w1h1[p]     = pkh(c0_.x, c0_.y);
                w1h1[4 + p] = pkh(c1_.x, c1_.y);
                float2 d0 = *(const float2*)(baseb + q * 8 + 2 * p);
                float2 d1 = *(const float2*)(baseb + 32 + q * 8 + 2 * p);
                b1h[p]     = pkh(d0.x, d0.y);
                b1h[4 + p] = pkh(d1.x, d1.y);
            }
            #pragma unroll
            for (int mt = 0; mt < 4; mt++) {
                w2A[mt][0] = ((const half8*)wsf)[((e * 4 + mt) * 2 + 0) * 64 + lane];
                w2A[mt][1] = ((const half8*)wsf)[((e * 4 + mt) * 2 + 1) * 64 + lane];
                float4 bb = ((const float4*)(b2 + e * 64))[mt * 4 + q];
                b2h[mt][0] = pkh(bb.x, bb.y);
                b2h[mt][1] = pkh(bb.z, bb.w);
                #pragma unroll
                for (int i = 0; i < 4; i++) {
                    int r = mt * 16 + q * 4 + i;
                    float2 wv = ((const float2*)(w3 + e * 128))[r];
                    w3h[mt][i] = pkh(wv.x, wv.y);
                }
            }
            b3r = ((const float2*)b3)[e];
        }
        // h1 in packed f16, directly into B-fragment layout:
        // B[k = ks*32 + q*8 + j][n = token n16]
        half2v xh0 = pkh(xv.x, xv.x);
        half2v xh1 = pkh(xv.y, xv.y);
        half8 bf0, bf1;
        #pragma unroll
        for (int p = 0; p < 4; p++) {
            half2v ha = w1h0[p] * xh0 + w1h1[p] * xh1 + b1h[p];
            half2v hb = w1h0[4 + p] * xh0 + w1h1[4 + p] * xh1 + b1h[4 + p];
            ha = __builtin_elementwise_max(ha, hz);
            hb = __builtin_elementwise_max(hb, hz);
            bf0[2 * p] = ha.x; bf0[2 * p + 1] = ha.y;
            bf1[2 * p] = hb.x; bf1[2 * p + 1] = hb.y;
        }
        // layer 2 MFMA + packed-f16 layer 3 epilogue, 2 accumulator chains
        half2v ya = hz, yb = hz;
        #pragma unroll
        for (int mt = 0; mt < 4; mt++) {
            f32x4 acc = {0.f, 0.f, 0.f, 0.f};
            acc = __builtin_amdgcn_mfma_f32_16x16x32_f16(w2A[mt][0], bf0, acc, 0, 0, 0);
            acc = __builtin_amdgcn_mfma_f32_16x16x32_f16(w2A[mt][1], bf1, acc, 0, 0, 0);
            // C-frag: col(token)=n16, row(hid_out)=mt*16+q*4+i
            half2v h01 = __builtin_elementwise_max(pkh(acc[0], acc[1]) + b2h[mt][0], hz);
            half2v h23 = __builtin_elementwise_max(pkh(acc[2], acc[3]) + b2h[mt][1], hz);
            half2v h0s = { h01.x, h01.x }, h1s = { h01.y, h01.y };
            half2v h2s = { h23.x, h23.x }, h3s = { h23.y, h23.y };
            half2v* acc01 = (mt & 2) ? &yb : &ya;
            *acc01 = *acc01 + h0s * w3h[mt][0];
            *acc01 = *acc01 + h1s * w3h[mt][1];
            *acc01 = *acc01 + h2s * w3h[mt][2];
            *acc01 = *acc01 + h3s * w3h[mt][3];
        }
        half2v yp = ya + yb;
        // reduce over the 4 lane-quads (hid_out split), packed
        float yr = __builtin_bit_cast(float, yp);
        yp = yp + __builtin_bit_cast(half2v, __shfl_xor(yr, 16));
        yr = __builtin_bit_cast(float, yp);
        yp = yp + __builtin_bit_cast(half2v, __shfl_xor(yr, 32));
        if (q == 0) {
            ysh[row + n16] = make_float2((float)yp.x + b3r.x, (float)yp.y + b3r.y);
        }
    }
    __syncthreads();

    // ---------------- Phase C: coalesced output ----------------
    #pragma unroll
    for (int i = 0; i < RPT; i++) {
        ((float2*)out)[base + i * TPB + t] = ysh[slotf[i]];
    }
}

extern "C" void kernel_launch(void* const* d_in, const int* in_sizes, int n_in,
                              void* d_out, int out_size, void* d_ws, size_t ws_size,
                              hipStream_t stream) {
    const float* x  = (const float*)d_in[0];
    const float* rW = (const float*)d_in[1];
    const float* rb = (const float*)d_in[2];
    const float* w1 = (const float*)d_in[3];
    const float* b1 = (const float*)d_in[4];
    const float* w2 = (const float*)d_in[5];
    const float* b2 = (const float*)d_in[6];
    const float* w3 = (const float*)d_in[7];
    const float* b3 = (const float*)d_in[8];
    float* out = (float*)d_out;
    _Float16* wsf = (_Float16*)d_ws;

    hipLaunchKernelGGL(prep_w2_frag, dim3(64), dim3(256), 0, stream, w2, wsf);
    hipLaunchKernelGGL(moe_kernel, dim3(NBLK), dim3(TPB), 0, stream,
                       x, rW, rb, w1, b1, b2, w3, b3, (const _Float16*)wsf, out);
}